// Round 1
// baseline (2559.874 us; speedup 1.0000x reference)
//
#include <hip/hip_runtime.h>

#define BATCH 16

// Build aux_T[(N+1)][16]: node-major transpose of x with a zero row at node 0.
__global__ void build_aux_T(const float* __restrict__ x, float* __restrict__ auxT, int n) {
    int idx = blockIdx.x * blockDim.x + threadIdx.x;  // over B*n, x-coalesced
    int total = BATCH * n;
    if (idx >= total) return;
    int b = idx / n;
    int i = idx % n;
    auxT[(i + 1) * BATCH + b] = x[idx];
    if (idx < BATCH) auxT[idx] = 0.0f;  // node-0 zero row
}

// One thread per edge; 16 batches per thread via float4 ops on node-major layout.
__global__ void edge_kernel(const float* __restrict__ param,
                            const int* __restrict__ src,
                            const int* __restrict__ des,
                            const float* __restrict__ auxT,
                            float* __restrict__ outT,
                            int E) {
    int e = blockIdx.x * blockDim.x + threadIdx.x;
    if (e >= E) return;
    float a = param[e];
    float w = param[E + e];
    float c = param[2 * E + e];
    int s = src[e];
    int d = des[e];
    const float4* vs4 = (const float4*)(auxT + (size_t)s * BATCH);
    const float4* vd4 = (const float4*)(auxT + (size_t)d * BATCH);
    float* os = outT + (size_t)s * BATCH;
    float* od = outT + (size_t)d * BATCH;
#pragma unroll
    for (int q = 0; q < 4; ++q) {
        float4 vs = vs4[q];
        float4 vd = vd4[q];
        float4 st;
        st.x = a * tanhf(w * (vs.x - vd.x) + c);
        st.y = a * tanhf(w * (vs.y - vd.y) + c);
        st.z = a * tanhf(w * (vs.z - vd.z) + c);
        st.w = a * tanhf(w * (vs.w - vd.w) + c);
        atomicAdd(os + q * 4 + 0, -st.x);
        atomicAdd(os + q * 4 + 1, -st.y);
        atomicAdd(os + q * 4 + 2, -st.z);
        atomicAdd(os + q * 4 + 3, -st.w);
        atomicAdd(od + q * 4 + 0, st.x);
        atomicAdd(od + q * 4 + 1, st.y);
        atomicAdd(od + q * 4 + 2, st.z);
        atomicAdd(od + q * 4 + 3, st.w);
    }
}

// out[b][i] = outT[i+1][b]  (drops node 0, writes every d_out element)
__global__ void write_out(const float* __restrict__ outT, float* __restrict__ out, int n) {
    int idx = blockIdx.x * blockDim.x + threadIdx.x;  // over B*n, out-coalesced
    if (idx >= BATCH * n) return;
    int b = idx / n;
    int i = idx % n;
    out[idx] = outT[(size_t)(i + 1) * BATCH + b];
}

// Fallback: direct atomics into d_out (used only if ws too small).
__global__ void edge_direct(const float* __restrict__ param,
                            const int* __restrict__ src,
                            const int* __restrict__ des,
                            const float* __restrict__ x,
                            float* __restrict__ out,
                            int E, int n) {
    int e = blockIdx.x * blockDim.x + threadIdx.x;
    if (e >= E) return;
    float a = param[e];
    float w = param[E + e];
    float c = param[2 * E + e];
    int s = src[e];
    int d = des[e];
#pragma unroll
    for (int b = 0; b < BATCH; ++b) {
        float vs = s ? x[(size_t)b * n + (s - 1)] : 0.0f;
        float vd = d ? x[(size_t)b * n + (d - 1)] : 0.0f;
        float st = a * tanhf(w * (vs - vd) + c);
        if (s) atomicAdd(out + (size_t)b * n + (s - 1), -st);
        if (d) atomicAdd(out + (size_t)b * n + (d - 1), st);
    }
}

extern "C" void kernel_launch(void* const* d_in, const int* in_sizes, int n_in,
                              void* d_out, int out_size, void* d_ws, size_t ws_size,
                              hipStream_t stream) {
    const float* x     = (const float*)d_in[1];
    const float* param = (const float*)d_in[2];
    const int*   src   = (const int*)d_in[3];
    const int*   des   = (const int*)d_in[4];
    float* out = (float*)d_out;

    int E = in_sizes[3];
    int n = in_sizes[1] / BATCH;  // N = 50000

    size_t auxBytes = (size_t)(n + 1) * BATCH * sizeof(float);
    size_t needed = 2 * auxBytes;

    if (ws_size >= needed) {
        float* auxT = (float*)d_ws;
        float* outT = (float*)((char*)d_ws + auxBytes);

        hipMemsetAsync(outT, 0, auxBytes, stream);

        int totalX = BATCH * n;
        build_aux_T<<<(totalX + 255) / 256, 256, 0, stream>>>(x, auxT, n);
        edge_kernel<<<(E + 255) / 256, 256, 0, stream>>>(param, src, des, auxT, outT, E);
        write_out<<<(totalX + 255) / 256, 256, 0, stream>>>(outT, out, n);
    } else {
        hipMemsetAsync(out, 0, (size_t)out_size * sizeof(float), stream);
        edge_direct<<<(E + 255) / 256, 256, 0, stream>>>(param, src, des, x, out, E, n);
    }
}